// Round 1
// baseline (632.107 us; speedup 1.0000x reference)
//
#include <hip/hip_runtime.h>
#include <math.h>

typedef __attribute__((ext_vector_type(4))) float f32x4;
typedef __attribute__((ext_vector_type(8))) short bf16x8;

__device__ inline short f2bf(float f) {
    union { float f; unsigned u; } v; v.f = f;
    unsigned u = v.u;
    u += 0x7fffu + ((u >> 16) & 1u);   // round-to-nearest-even
    return (short)(u >> 16);
}

// ---------------- avgpool + sinusoidal bias init ----------------
// blocks 0..511: segment-average x -> altx.  blocks 512..543: s = sinusoidal bias
__global__ __launch_bounds__(256) void k_avg_init(const float* __restrict__ x,
                                                  float* __restrict__ altx,
                                                  float* __restrict__ s) {
    int blk = blockIdx.x, t = threadIdx.x;
    if (blk < 512) {
        int wv = t >> 6, lane = t & 63;
        int p = blk * 4 + wv;              // p = c2*64 + c1
        const float* row = x + (size_t)p * 2048;
        int c2 = p >> 6, c1 = p & 63;
        int m = c1 * 32 + c2;
        for (int seg = 0; seg < 32; ++seg) {
            float v = row[seg * 64 + lane];
            for (int off = 32; off; off >>= 1) v += __shfl_xor(v, off, 64);
            if (lane == 0) altx[seg * 2048 + m] = v * (1.0f / 64.0f);
        }
    } else {
        int i = blk - 512;                 // token row
        const float kln = logf(10000.0f) / 1024.0f;
        for (int l = t; l < 2048; l += 256) {
            int c = l & ~1;                // even column index drives the angle
            float ang = (float)i * expf(-(float)c * kln);
            s[i * 2048 + l] = (l & 1) ? cosf(ang) : sinf(ang);
        }
    }
}

// ---------------- row stats (block = one row of 2048) ----------------
__device__ inline void row_stats(const float* __restrict__ row, float& mu, float& rstd) {
    float sm = 0.f, ss = 0.f;
    for (int idx = threadIdx.x; idx < 2048; idx += 256) {
        float v = row[idx]; sm += v; ss += v * v;
    }
    for (int off = 32; off; off >>= 1) {
        sm += __shfl_xor(sm, off, 64);
        ss += __shfl_xor(ss, off, 64);
    }
    __shared__ float as[4], bs[4];
    int wv = threadIdx.x >> 6, lane = threadIdx.x & 63;
    if (lane == 0) { as[wv] = sm; bs[wv] = ss; }
    __syncthreads();
    sm = as[0] + as[1] + as[2] + as[3];
    ss = bs[0] + bs[1] + bs[2] + bs[3];
    mu = sm * (1.0f / 2048.0f);
    float var = ss * (1.0f / 2048.0f) - mu * mu;
    rstd = rsqrtf(var + 1e-5f);
}

// blocks 0..31: y = LN1(s).  blocks 32..55: zero qkv (196608 floats)
__global__ __launch_bounds__(256) void k_prep1(const float* __restrict__ s,
                                               const float* __restrict__ g,
                                               const float* __restrict__ b,
                                               float* __restrict__ y,
                                               float* __restrict__ qkv) {
    int blk = blockIdx.x;
    if (blk < 32) {
        const float* row = s + blk * 2048;
        float mu, rstd; row_stats(row, mu, rstd);
        float* yr = y + blk * 2048;
        for (int idx = threadIdx.x; idx < 2048; idx += 256)
            yr[idx] = (row[idx] - mu) * rstd * g[idx] + b[idx];
    } else {
        int z = blk - 32;
        float4* p4 = (float4*)(qkv + (size_t)z * 8192);
        float4 zero = {0.f, 0.f, 0.f, 0.f};
        for (int idx = threadIdx.x; idx < 2048; idx += 256) p4[idx] = zero;
    }
}

// blocks 0..15: per-head scalar attn + serial cumsum -> imv.  blocks 16..47: s2 = s
__global__ __launch_bounds__(256) void k_scan(const float* __restrict__ qkv,
                                              const float* __restrict__ s,
                                              float* __restrict__ imv,
                                              float* __restrict__ s2) {
    int blk = blockIdx.x, t = threadIdx.x;
    if (blk < 16) {
        int h = blk;
        __shared__ float rsa[32];
        if (t < 32) {
            const float* qr = qkv + (size_t)t * 6144 + h * 128;
            const float* kr = qr + 2048;
            float acc = 0.f;
            for (int d = 0; d < 128; ++d) acc += qr[d] * kr[d];
            rsa[t] = acc * 0.08838834764831845f;   // 1/sqrt(128)
        }
        __syncthreads();
        if (t < 128) {
            float acc = 0.f;
            for (int i = 0; i < 32; ++i) {
                acc += rsa[i] * qkv[(size_t)i * 6144 + 4096 + h * 128 + t];
                imv[i * 2048 + h * 128 + t] = acc;
            }
        }
    } else {
        int z = blk - 16;
        const float4* sp = (const float4*)(s + (size_t)z * 2048);
        float4* dp = (float4*)(s2 + (size_t)z * 2048);
        for (int idx = t; idx < 512; idx += 256) dp[idx] = sp[idx];
    }
}

// blocks 0..31: sout = LN2(s2)+s2.  blocks 32..63: zero h (262144 floats)
__global__ __launch_bounds__(256) void k_prep2(const float* __restrict__ s2,
                                               const float* __restrict__ g,
                                               const float* __restrict__ b,
                                               float* __restrict__ sout,
                                               float* __restrict__ h) {
    int blk = blockIdx.x;
    if (blk < 32) {
        const float* row = s2 + blk * 2048;
        float mu, rstd; row_stats(row, mu, rstd);
        float* sr = sout + blk * 2048;
        for (int idx = threadIdx.x; idx < 2048; idx += 256) {
            float v = row[idx];
            sr[idx] = (v - mu) * rstd * g[idx] + b[idx] + v;
        }
    } else {
        int z = blk - 32;
        float4* p4 = (float4*)(h + (size_t)z * 8192);
        float4 zero = {0.f, 0.f, 0.f, 0.f};
        for (int idx = threadIdx.x; idx < 2048; idx += 256) p4[idx] = zero;
    }
}

// blocks 0..127: h = gelu(h + fc1_b).  blocks 128..159: sout = broadcast(fc2_b)
__global__ __launch_bounds__(256) void k_act(float* __restrict__ h,
                                             const float* __restrict__ fc1_b,
                                             float* __restrict__ sout,
                                             const float* __restrict__ fc2_b) {
    int blk = blockIdx.x, t = threadIdx.x;
    if (blk < 128) {
        size_t base = ((size_t)blk * 256 + t) * 8;
        #pragma unroll
        for (int j = 0; j < 8; ++j) {
            size_t idx = base + j;
            float v = h[idx] + fc1_b[idx & 8191];
            h[idx] = 0.5f * v * (1.0f + erff(v * 0.70710678118654752f));
        }
    } else {
        size_t base = ((size_t)(blk - 128) * 256 + t) * 8;
        #pragma unroll
        for (int j = 0; j < 8; ++j) {
            size_t idx = base + j;
            sout[idx] = fc2_b[idx & 2047];
        }
    }
}

// ---------------- skinny GEMM: out[32][N] += act[32][K] @ W[N][K]^T ----------------
// grid (N/64, S); 4 waves/block, 16 cols/wave, split-K via fp32 atomics.
__global__ __launch_bounds__(256) void k_gemm(const float* __restrict__ W,
                                              const float* __restrict__ act,
                                              float* __restrict__ out,
                                              int N, int K, int kchunk) {
    int t = threadIdx.x;
    int lane = t & 63, wv = t >> 6;
    int m = lane & 15, q = lane >> 4;
    int nb = blockIdx.x * 64 + wv * 16;
    size_t kbeg = (size_t)blockIdx.y * kchunk;
    const float* A0 = act + (size_t)m * K + kbeg + q * 8;
    const float* A1 = A0 + (size_t)16 * K;
    const float* B  = W + (size_t)(nb + m) * K + kbeg + q * 8;
    f32x4 acc0 = {0.f, 0.f, 0.f, 0.f};
    f32x4 acc1 = {0.f, 0.f, 0.f, 0.f};
    for (int k = 0; k < kchunk; k += 32) {
        float4 a0l = *(const float4*)(A0 + k);
        float4 a0h = *(const float4*)(A0 + k + 4);
        float4 a1l = *(const float4*)(A1 + k);
        float4 a1h = *(const float4*)(A1 + k + 4);
        float4 bl  = *(const float4*)(B + k);
        float4 bh  = *(const float4*)(B + k + 4);
        bf16x8 fa0 = { f2bf(a0l.x), f2bf(a0l.y), f2bf(a0l.z), f2bf(a0l.w),
                       f2bf(a0h.x), f2bf(a0h.y), f2bf(a0h.z), f2bf(a0h.w) };
        bf16x8 fa1 = { f2bf(a1l.x), f2bf(a1l.y), f2bf(a1l.z), f2bf(a1l.w),
                       f2bf(a1h.x), f2bf(a1h.y), f2bf(a1h.z), f2bf(a1h.w) };
        bf16x8 fb  = { f2bf(bl.x),  f2bf(bl.y),  f2bf(bl.z),  f2bf(bl.w),
                       f2bf(bh.x),  f2bf(bh.y),  f2bf(bh.z),  f2bf(bh.w) };
        acc0 = __builtin_amdgcn_mfma_f32_16x16x32_bf16(fa0, fb, acc0, 0, 0, 0);
        acc1 = __builtin_amdgcn_mfma_f32_16x16x32_bf16(fa1, fb, acc1, 0, 0, 0);
    }
    // C/D layout: col = lane&15, row = (lane>>4)*4 + reg
    float* op = out + (size_t)(q * 4) * N + nb + m;
    #pragma unroll
    for (int r = 0; r < 4; ++r) {
        atomicAdd(op + (size_t)r * N, acc0[r]);
        atomicAdd(op + (size_t)(r + 16) * N, acc1[r]);
    }
}

extern "C" void kernel_launch(void* const* d_in, const int* in_sizes, int n_in,
                              void* d_out, int out_size, void* d_ws, size_t ws_size,
                              hipStream_t stream) {
    const float* x      = (const float*)d_in[0];
    const float* weight = (const float*)d_in[1];
    const float* Wqkv   = (const float*)d_in[2];
    const float* Wo     = (const float*)d_in[3];
    const float* ln1_g  = (const float*)d_in[4];
    const float* ln1_b  = (const float*)d_in[5];
    const float* ln2_g  = (const float*)d_in[6];
    const float* ln2_b  = (const float*)d_in[7];
    const float* fc1_w  = (const float*)d_in[8];
    const float* fc1_b  = (const float*)d_in[9];
    const float* fc2_w  = (const float*)d_in[10];
    const float* fc2_b  = (const float*)d_in[11];
    float* ws   = (float*)d_ws;
    float* altx = ws;                    // 65536 f
    float* sbuf = ws + 65536;            // 65536 f
    float* y    = ws + 131072;           // 65536 f
    float* s2   = ws + 196608;           // 65536 f
    float* imv  = ws + 262144;           // 65536 f
    float* qkv  = ws + 327680;           // 196608 f
    float* h    = ws + 524288;           // 262144 f  (total 3 MB)
    float* outF = (float*)d_out;

    k_avg_init<<<544, 256, 0, stream>>>(x, altx, sbuf);
    k_gemm<<<dim3(32, 16), 256, 0, stream>>>(weight, altx, sbuf, 2048, 2048, 128);
    for (int a = 0; a < 3; ++a) {
        k_prep1<<<56, 256, 0, stream>>>(sbuf, ln1_g, ln1_b, y, qkv);
        k_gemm<<<dim3(96, 8), 256, 0, stream>>>(Wqkv + (size_t)a * 12582912, y, qkv, 6144, 2048, 256);
        k_scan<<<48, 256, 0, stream>>>(qkv, sbuf, imv, s2);
        k_gemm<<<dim3(32, 16), 256, 0, stream>>>(Wo + (size_t)a * 4194304, imv, s2, 2048, 2048, 128);
        k_prep2<<<64, 256, 0, stream>>>(s2, ln2_g, ln2_b, sbuf, h);
        k_gemm<<<dim3(128, 4), 256, 0, stream>>>(fc1_w, sbuf, h, 8192, 2048, 512);
        float* sout = (a == 2) ? outF : sbuf;
        k_act<<<160, 256, 0, stream>>>(h, fc1_b, sout, fc2_b);
        k_gemm<<<dim3(32, 16), 256, 0, stream>>>(fc2_w, h, sout, 2048, 8192, 512);
    }
}

// Round 2
// 618.774 us; speedup vs baseline: 1.0215x; 1.0215x over previous
//
#include <hip/hip_runtime.h>
#include <math.h>

typedef __attribute__((ext_vector_type(4))) float f32x4;
typedef __attribute__((ext_vector_type(8))) short bf16x8;

__device__ inline short f2bf(float f) {
    union { float f; unsigned u; } v; v.f = f;
    unsigned u = v.u;
    u += 0x7fffu + ((u >> 16) & 1u);   // round-to-nearest-even
    return (short)(u >> 16);
}

// ---------------- avgpool + sinusoidal bias init ----------------
// blocks 0..511: segment-average x -> altx.  blocks 512..543: s = sinusoidal bias
__global__ __launch_bounds__(256) void k_avg_init(const float* __restrict__ x,
                                                  float* __restrict__ altx,
                                                  float* __restrict__ s) {
    int blk = blockIdx.x, t = threadIdx.x;
    if (blk < 512) {
        int wv = t >> 6, lane = t & 63;
        int p = blk * 4 + wv;              // p = c2*64 + c1
        const float* row = x + (size_t)p * 2048;
        int c2 = p >> 6, c1 = p & 63;
        int m = c1 * 32 + c2;
        for (int seg = 0; seg < 32; ++seg) {
            float v = row[seg * 64 + lane];
            for (int off = 32; off; off >>= 1) v += __shfl_xor(v, off, 64);
            if (lane == 0) altx[seg * 2048 + m] = v * (1.0f / 64.0f);
        }
    } else {
        int i = blk - 512;                 // token row
        const float kln = logf(10000.0f) / 1024.0f;
        for (int l = t; l < 2048; l += 256) {
            int c = l & ~1;                // even column index drives the angle
            float ang = (float)i * expf(-(float)c * kln);
            s[i * 2048 + l] = (l & 1) ? cosf(ang) : sinf(ang);
        }
    }
}

// ---------------- row stats (block = one row of 2048) ----------------
__device__ inline void row_stats(const float* __restrict__ row, float& mu, float& rstd) {
    float sm = 0.f, ss = 0.f;
    for (int idx = threadIdx.x; idx < 2048; idx += 256) {
        float v = row[idx]; sm += v; ss += v * v;
    }
    for (int off = 32; off; off >>= 1) {
        sm += __shfl_xor(sm, off, 64);
        ss += __shfl_xor(ss, off, 64);
    }
    __shared__ float as[4], bs[4];
    int wv = threadIdx.x >> 6, lane = threadIdx.x & 63;
    if (lane == 0) { as[wv] = sm; bs[wv] = ss; }
    __syncthreads();
    sm = as[0] + as[1] + as[2] + as[3];
    ss = bs[0] + bs[1] + bs[2] + bs[3];
    mu = sm * (1.0f / 2048.0f);
    float var = ss * (1.0f / 2048.0f) - mu * mu;
    rstd = rsqrtf(var + 1e-5f);
}

// blocks 0..31: y = LN1(s).  blocks 32..55: zero qkv (196608 floats)
__global__ __launch_bounds__(256) void k_prep1(const float* __restrict__ s,
                                               const float* __restrict__ g,
                                               const float* __restrict__ b,
                                               float* __restrict__ y,
                                               float* __restrict__ qkv) {
    int blk = blockIdx.x;
    if (blk < 32) {
        const float* row = s + blk * 2048;
        float mu, rstd; row_stats(row, mu, rstd);
        float* yr = y + blk * 2048;
        for (int idx = threadIdx.x; idx < 2048; idx += 256)
            yr[idx] = (row[idx] - mu) * rstd * g[idx] + b[idx];
    } else {
        int z = blk - 32;
        float4* p4 = (float4*)(qkv + (size_t)z * 8192);
        float4 zero = {0.f, 0.f, 0.f, 0.f};
        for (int idx = threadIdx.x; idx < 2048; idx += 256) p4[idx] = zero;
    }
}

// blocks 0..15: per-head scalar attn + serial cumsum -> imv.  blocks 16..47: s2 = s
__global__ __launch_bounds__(256) void k_scan(const float* __restrict__ qkv,
                                              const float* __restrict__ s,
                                              float* __restrict__ imv,
                                              float* __restrict__ s2) {
    int blk = blockIdx.x, t = threadIdx.x;
    if (blk < 16) {
        int h = blk;
        __shared__ float rsa[32];
        if (t < 32) {
            const float* qr = qkv + (size_t)t * 6144 + h * 128;
            const float* kr = qr + 2048;
            float acc = 0.f;
            for (int d = 0; d < 128; ++d) acc += qr[d] * kr[d];
            rsa[t] = acc * 0.08838834764831845f;   // 1/sqrt(128)
        }
        __syncthreads();
        if (t < 128) {
            float acc = 0.f;
            for (int i = 0; i < 32; ++i) {
                acc += rsa[i] * qkv[(size_t)i * 6144 + 4096 + h * 128 + t];
                imv[i * 2048 + h * 128 + t] = acc;
            }
        }
    } else {
        int z = blk - 16;
        const float4* sp = (const float4*)(s + (size_t)z * 2048);
        float4* dp = (float4*)(s2 + (size_t)z * 2048);
        for (int idx = t; idx < 512; idx += 256) dp[idx] = sp[idx];
    }
}

// blocks 0..31: sout = LN2(s2)+s2.  blocks 32..63: zero h (262144 floats)
__global__ __launch_bounds__(256) void k_prep2(const float* __restrict__ s2,
                                               const float* __restrict__ g,
                                               const float* __restrict__ b,
                                               float* __restrict__ sout,
                                               float* __restrict__ h) {
    int blk = blockIdx.x;
    if (blk < 32) {
        const float* row = s2 + blk * 2048;
        float mu, rstd; row_stats(row, mu, rstd);
        float* sr = sout + blk * 2048;
        for (int idx = threadIdx.x; idx < 2048; idx += 256) {
            float v = row[idx];
            sr[idx] = (v - mu) * rstd * g[idx] + b[idx] + v;
        }
    } else {
        int z = blk - 32;
        float4* p4 = (float4*)(h + (size_t)z * 8192);
        float4 zero = {0.f, 0.f, 0.f, 0.f};
        for (int idx = threadIdx.x; idx < 2048; idx += 256) p4[idx] = zero;
    }
}

// blocks 0..127: h = gelu(h + fc1_b).  blocks 128..159: sout = broadcast(fc2_b)
__global__ __launch_bounds__(256) void k_act(float* __restrict__ h,
                                             const float* __restrict__ fc1_b,
                                             float* __restrict__ sout,
                                             const float* __restrict__ fc2_b) {
    int blk = blockIdx.x, t = threadIdx.x;
    if (blk < 128) {
        size_t base = ((size_t)blk * 256 + t) * 8;
        #pragma unroll
        for (int j = 0; j < 8; ++j) {
            size_t idx = base + j;
            float v = h[idx] + fc1_b[idx & 8191];
            h[idx] = 0.5f * v * (1.0f + erff(v * 0.70710678118654752f));
        }
    } else {
        size_t base = ((size_t)(blk - 128) * 256 + t) * 8;
        #pragma unroll
        for (int j = 0; j < 8; ++j) {
            size_t idx = base + j;
            sout[idx] = fc2_b[idx & 2047];
        }
    }
}

// ---------------- skinny GEMM: out[32][N] += act[32][K] @ W[N][K]^T ----------------
// grid (N/64, K/(NIT*32)); 4 waves/block, 16 cols/wave, split-K via fp32 atomics.
// NIT is compile-time so the K-loop fully unrolls: all loads hoist/pipeline ->
// deep MLP instead of per-iteration vmcnt(0) serialization.
template<int NIT>
__global__ __launch_bounds__(256, 2) void k_gemm(const float* __restrict__ W,
                                                 const float* __restrict__ act,
                                                 float* __restrict__ out,
                                                 int N, int K) {
    int t = threadIdx.x;
    int lane = t & 63, wv = t >> 6;
    int m = lane & 15, q = lane >> 4;
    int nb = blockIdx.x * 64 + wv * 16;
    size_t kbeg = (size_t)blockIdx.y * (NIT * 32);
    const float* A0 = act + (size_t)m * K + kbeg + q * 8;
    const float* A1 = A0 + (size_t)16 * K;
    const float* B  = W + (size_t)(nb + m) * K + kbeg + q * 8;
    f32x4 acc0 = {0.f, 0.f, 0.f, 0.f};
    f32x4 acc1 = {0.f, 0.f, 0.f, 0.f};

    float4 a0l = *(const float4*)(A0);
    float4 a0h = *(const float4*)(A0 + 4);
    float4 a1l = *(const float4*)(A1);
    float4 a1h = *(const float4*)(A1 + 4);
    float4 bl  = *(const float4*)(B);
    float4 bh  = *(const float4*)(B + 4);

    #pragma unroll
    for (int it = 0; it < NIT; ++it) {
        float4 c0l = a0l, c0h = a0h, c1l = a1l, c1h = a1h, cbl = bl, cbh = bh;
        if (it + 1 < NIT) {                 // issue next loads before converting
            int k = (it + 1) * 32;
            a0l = *(const float4*)(A0 + k);
            a0h = *(const float4*)(A0 + k + 4);
            a1l = *(const float4*)(A1 + k);
            a1h = *(const float4*)(A1 + k + 4);
            bl  = *(const float4*)(B + k);
            bh  = *(const float4*)(B + k + 4);
        }
        bf16x8 fa0 = { f2bf(c0l.x), f2bf(c0l.y), f2bf(c0l.z), f2bf(c0l.w),
                       f2bf(c0h.x), f2bf(c0h.y), f2bf(c0h.z), f2bf(c0h.w) };
        bf16x8 fa1 = { f2bf(c1l.x), f2bf(c1l.y), f2bf(c1l.z), f2bf(c1l.w),
                       f2bf(c1h.x), f2bf(c1h.y), f2bf(c1h.z), f2bf(c1h.w) };
        bf16x8 fb  = { f2bf(cbl.x), f2bf(cbl.y), f2bf(cbl.z), f2bf(cbl.w),
                       f2bf(cbh.x), f2bf(cbh.y), f2bf(cbh.z), f2bf(cbh.w) };
        acc0 = __builtin_amdgcn_mfma_f32_16x16x32_bf16(fa0, fb, acc0, 0, 0, 0);
        acc1 = __builtin_amdgcn_mfma_f32_16x16x32_bf16(fa1, fb, acc1, 0, 0, 0);
    }
    // C/D layout: col = lane&15, row = (lane>>4)*4 + reg
    float* op = out + (size_t)(q * 4) * N + nb + m;
    #pragma unroll
    for (int r = 0; r < 4; ++r) {
        atomicAdd(op + (size_t)r * N, acc0[r]);
        atomicAdd(op + (size_t)(r + 16) * N, acc1[r]);
    }
}

extern "C" void kernel_launch(void* const* d_in, const int* in_sizes, int n_in,
                              void* d_out, int out_size, void* d_ws, size_t ws_size,
                              hipStream_t stream) {
    const float* x      = (const float*)d_in[0];
    const float* weight = (const float*)d_in[1];
    const float* Wqkv   = (const float*)d_in[2];
    const float* Wo     = (const float*)d_in[3];
    const float* ln1_g  = (const float*)d_in[4];
    const float* ln1_b  = (const float*)d_in[5];
    const float* ln2_g  = (const float*)d_in[6];
    const float* ln2_b  = (const float*)d_in[7];
    const float* fc1_w  = (const float*)d_in[8];
    const float* fc1_b  = (const float*)d_in[9];
    const float* fc2_w  = (const float*)d_in[10];
    const float* fc2_b  = (const float*)d_in[11];
    float* ws   = (float*)d_ws;
    float* altx = ws;                    // 65536 f
    float* sbuf = ws + 65536;            // 65536 f
    float* y    = ws + 131072;           // 65536 f
    float* s2   = ws + 196608;           // 65536 f
    float* imv  = ws + 262144;           // 65536 f
    float* qkv  = ws + 327680;           // 196608 f
    float* h    = ws + 524288;           // 262144 f  (total 3 MB)
    float* outF = (float*)d_out;

    k_avg_init<<<544, 256, 0, stream>>>(x, altx, sbuf);
    k_gemm<4><<<dim3(32, 16), 256, 0, stream>>>(weight, altx, sbuf, 2048, 2048);
    for (int a = 0; a < 3; ++a) {
        k_prep1<<<56, 256, 0, stream>>>(sbuf, ln1_g, ln1_b, y, qkv);
        k_gemm<4><<<dim3(96, 16), 256, 0, stream>>>(Wqkv + (size_t)a * 12582912, y, qkv, 6144, 2048);
        k_scan<<<48, 256, 0, stream>>>(qkv, sbuf, imv, s2);
        k_gemm<4><<<dim3(32, 16), 256, 0, stream>>>(Wo + (size_t)a * 4194304, imv, s2, 2048, 2048);
        k_prep2<<<64, 256, 0, stream>>>(s2, ln2_g, ln2_b, sbuf, h);
        k_gemm<4><<<dim3(128, 16), 256, 0, stream>>>(fc1_w, sbuf, h, 8192, 2048);
        float* sout = (a == 2) ? outF : sbuf;
        k_act<<<160, 256, 0, stream>>>(h, fc1_b, sout, fc2_b);
        k_gemm<4><<<dim3(32, 64), 256, 0, stream>>>(fc2_w, h, sout, 2048, 8192);
    }
}